// Round 1
// 156.629 us; speedup vs baseline: 1.0020x; 1.0020x over previous
//
#include <hip/hip_runtime.h>

// Problem constants (from reference): BZ=64, P=512, T=256, H=768
#define BZ 64
#define P  512
#define T  256
#define H  768
#define H4 (H / 4)                // 192 float4 per row
#define THREADS 256
#define F4PT 4                    // float4 outputs per thread
#define F4PB (THREADS * F4PT)     // 1024 float4 per block
#define OUT4B (T * H4)            // 49152 float4 per batch
#define CPB (OUT4B / F4PB)        // 48 chunks (blocks) per batch

// Fused kernel: per-block wave-shfl scan of this batch's lens (cheap,
// redundant across the batch's 48 blocks), then coalesced gather/average.
//
// Key invariants:
//  - lens[] in {0,1,2} by construction (generator: integers(1,3), zero tail).
//    len==2 path specialized (two independent loads, *0.5f); general loop
//    kept as never-taken fallback.
//  - 192 = 3*64, and every block/q offset is a multiple of 64, so each
//    wave's 64 consecutive f4 indices lie inside ONE token: branches are
//    wave-uniform, row loads are contiguous 1KB per wave.
__global__ __launch_bounds__(THREADS) void fused_kernel(
    const float* __restrict__ enc,
    const int* __restrict__ lens,
    float* __restrict__ out)
{
    __shared__ int s_start[T];
    __shared__ int s_len[T];
    __shared__ int s_wsum[THREADS / 64];

    const int tid  = threadIdx.x;
    const int lane = tid & 63;
    const int wid  = tid >> 6;
    const int b    = blockIdx.x / CPB;
    const int c    = blockIdx.x % CPB;

    // ---- per-block exclusive scan of lens[b][*] (4 waves, shfl scan) ----
    const int v = lens[b * T + tid];
    int x = v;
    #pragma unroll
    for (int off = 1; off < 64; off <<= 1) {
        const int y = __shfl_up(x, off, 64);
        if (lane >= off) x += y;
    }
    if (lane == 63) s_wsum[wid] = x;
    __syncthreads();
    int woff = 0;
    #pragma unroll
    for (int w = 0; w < THREADS / 64; ++w)
        woff += (w < wid) ? s_wsum[w] : 0;
    s_start[tid] = x + woff - v;   // exclusive prefix = first subword row
    s_len[tid]   = v;
    __syncthreads();

    // ---- gather: block covers f4 range [c*F4PB, (c+1)*F4PB) of batch b ----
    const float4* encb = (const float4*)enc + (size_t)b * P * H4;
    float4*       outb = (float4*)out + (size_t)b * OUT4B;
    const int base = c * F4PB + tid;

    int           lq[F4PT];
    const float4* rq[F4PT];
    float4 r0[F4PT], r1[F4PT];

    // Phase 1: token lookup + addresses (LDS broadcast reads, all cheap)
    #pragma unroll
    for (int q = 0; q < F4PT; ++q) {
        const int f4 = base + q * THREADS;
        const int t  = f4 / H4;          // token index (wave-uniform)
        const int h4 = f4 - t * H4;
        lq[q] = s_len[t];
        rq[q] = encb + (size_t)s_start[t] * H4 + h4;
    }
    // Phase 2: issue all first-row loads (4 independent 1KB wave loads)
    #pragma unroll
    for (int q = 0; q < F4PT; ++q) {
        r0[q] = (lq[q] > 0) ? rq[q][0]
                            : make_float4(0.f, 0.f, 0.f, 0.f);
    }
    // Phase 3: issue all second-row loads (len==2 tokens)
    #pragma unroll
    for (int q = 0; q < F4PT; ++q) {
        r1[q] = (lq[q] > 1) ? rq[q][H4]
                            : make_float4(0.f, 0.f, 0.f, 0.f);
    }
    // Phase 4: combine + store (len==0 stays exactly zero)
    #pragma unroll
    for (int q = 0; q < F4PT; ++q) {
        float4 r = r0[q];
        const int len = lq[q];
        if (len > 1) {
            r.x += r1[q].x; r.y += r1[q].y; r.z += r1[q].z; r.w += r1[q].w;
            if (len > 2) {  // never taken for this generator; kept for safety
                #pragma unroll 1
                for (int k = 2; k < len; ++k) {
                    const float4 e = rq[q][(size_t)k * H4];
                    r.x += e.x; r.y += e.y; r.z += e.z; r.w += e.w;
                }
            }
            const float inv = 1.0f / (float)len;  // exact for len=2 (pow2)
            r.x *= inv; r.y *= inv; r.z *= inv; r.w *= inv;
        }
        outb[base + q * THREADS] = r;
    }
}

extern "C" void kernel_launch(void* const* d_in, const int* in_sizes, int n_in,
                              void* d_out, int out_size, void* d_ws, size_t ws_size,
                              hipStream_t stream)
{
    const float* enc  = (const float*)d_in[0];  // enc_out (BZ,P,H) f32
    // d_in[1] = bert_mask (unused; redundant with lens)
    const int*   lens = (const int*)d_in[2];    // bert_lens (BZ,T) i32
    float*       out  = (float*)d_out;          // (BZ,T,H) f32
    (void)d_ws; (void)ws_size; (void)in_sizes; (void)n_in; (void)out_size;

    fused_kernel<<<BZ * CPB, THREADS, 0, stream>>>(enc, lens, out);
}

// Round 3
// 156.606 us; speedup vs baseline: 1.0022x; 1.0001x over previous
//
#include <hip/hip_runtime.h>

// Problem constants (from reference): BZ=64, P=512, T=256, H=768
#define BZ 64
#define P  512
#define T  256
#define H  768
#define H4 (H / 4)                // 192 float4 per row
#define THREADS 256
#define F4PT 4                    // float4 outputs per thread
#define F4PB (THREADS * F4PT)     // 1024 float4 per block
#define OUT4B (T * H4)            // 49152 float4 per batch
#define CPB (OUT4B / F4PB)        // 48 chunks (blocks) per batch

// Native clang vector for __builtin_nontemporal_store (HIP float4 is a
// struct wrapper and is rejected by the builtin; layout is identical).
typedef float f32x4 __attribute__((ext_vector_type(4)));

// Fused scan + gather, BRANCH-FREE load stream:
//  - per-block wave-shfl exclusive scan of this batch's lens (cheap, redundant
//    across the batch's 48 blocks; avoids a second kernel + d_ws round-trip).
//  - every thread issues its 8 row-loads UNCONDITIONALLY:
//      len==0 -> load batch row 0 twice, scale 0        (safe dummy, L2-hot)
//      len==1 -> load row start twice,  scale 1/2       (dup hits L2, no HBM)
//      len==2 -> load rows start,start+1, scale 1/2
//    This removes all wave-uniform branches around global_load_dwordx4 so the
//    compiler can cluster all 8 independent 1KB wave-loads back-to-back.
//  - output stores are NON-TEMPORAL (never re-read): keeps L2 clean for the
//    duplicate-row load hits.
//  - 192 = 3*64 and all offsets are multiples of 64, so each wave's 64
//    consecutive f4 indices lie inside ONE token: everything wave-uniform,
//    loads/stores fully coalesced.
__global__ __launch_bounds__(THREADS) void fused_kernel(
    const float* __restrict__ enc,
    const int* __restrict__ lens,
    float* __restrict__ out)
{
    __shared__ int s_start[T];
    __shared__ int s_len[T];
    __shared__ int s_wsum[THREADS / 64];

    const int tid  = threadIdx.x;
    const int lane = tid & 63;
    const int wid  = tid >> 6;
    const int b    = blockIdx.x / CPB;
    const int c    = blockIdx.x % CPB;

    // ---- per-block exclusive scan of lens[b][*] (4 waves, shfl scan) ----
    const int v = lens[b * T + tid];
    int x = v;
    #pragma unroll
    for (int off = 1; off < 64; off <<= 1) {
        const int y = __shfl_up(x, off, 64);
        if (lane >= off) x += y;
    }
    if (lane == 63) s_wsum[wid] = x;
    __syncthreads();
    int woff = 0;
    #pragma unroll
    for (int w = 0; w < THREADS / 64; ++w)
        woff += (w < wid) ? s_wsum[w] : 0;
    s_start[tid] = x + woff - v;   // exclusive prefix = first subword row
    s_len[tid]   = v;
    __syncthreads();

    // ---- gather: block covers f4 range [c*F4PB, (c+1)*F4PB) of batch b ----
    const float4* encb = (const float4*)enc + (size_t)b * P * H4;
    float4*       outb = (float4*)out + (size_t)b * OUT4B;
    const int base = c * F4PB + tid;

    int           lq[F4PT];
    const float4* aq[F4PT];   // first-row address (always valid)
    const float4* bq[F4PT];   // second-row address (always valid)
    float4 r0[F4PT], r1[F4PT];

    // Phase 1: token lookup + safe addresses (LDS broadcast reads, cheap)
    #pragma unroll
    for (int q = 0; q < F4PT; ++q) {
        const int f4 = base + q * THREADS;
        const int t  = f4 / H4;              // wave-uniform token index
        const int h4 = f4 - t * H4;
        const int len   = s_len[t];
        const int start = s_start[t];
        const int row0  = (len > 0) ? start : 0;         // dummy row 0 if empty
        const int row1  = (len > 1) ? start + 1 : row0;  // dup row if len<=1
        lq[q] = len;
        aq[q] = encb + (size_t)row0 * H4 + h4;
        bq[q] = encb + (size_t)row1 * H4 + h4;
    }
    // Phase 2+3: issue all 8 loads unconditionally (8 independent wave-loads)
    #pragma unroll
    for (int q = 0; q < F4PT; ++q) r0[q] = aq[q][0];
    #pragma unroll
    for (int q = 0; q < F4PT; ++q) r1[q] = bq[q][0];
    // Phase 4: combine + scale + NT store
    #pragma unroll
    for (int q = 0; q < F4PT; ++q) {
        const int len = lq[q];
        f32x4 r;
        r.x = r0[q].x + r1[q].x;
        r.y = r0[q].y + r1[q].y;
        r.z = r0[q].z + r1[q].z;
        r.w = r0[q].w + r1[q].w;
        if (len > 2) {  // never taken for this generator; kept for correctness
            #pragma unroll 1
            for (int k = 2; k < len; ++k) {
                const float4 e = aq[q][(size_t)k * H4];
                r.x += e.x; r.y += e.y; r.z += e.z; r.w += e.w;
            }
        }
        // len==0 -> 0; len==1 -> (2a)*1/2 = a; len>=2 -> sum * 1/len
        const float denom = (float)(len + (len == 1));
        const float inv   = (len > 0) ? (1.0f / denom) : 0.0f;
        r *= inv;
        __builtin_nontemporal_store(
            r, reinterpret_cast<f32x4*>(&outb[base + q * THREADS]));
    }
}

extern "C" void kernel_launch(void* const* d_in, const int* in_sizes, int n_in,
                              void* d_out, int out_size, void* d_ws, size_t ws_size,
                              hipStream_t stream)
{
    const float* enc  = (const float*)d_in[0];  // enc_out (BZ,P,H) f32
    // d_in[1] = bert_mask (unused; redundant with lens)
    const int*   lens = (const int*)d_in[2];    // bert_lens (BZ,T) i32
    float*       out  = (float*)d_out;          // (BZ,T,H) f32
    (void)d_ws; (void)ws_size; (void)in_sizes; (void)n_in; (void)out_size;

    fused_kernel<<<BZ * CPB, THREADS, 0, stream>>>(enc, lens, out);
}